// Round 3
// baseline (105.492 us; speedup 1.0000x reference)
//
#include <hip/hip_runtime.h>

#define DIM 256
#define NPIX 4096
#define BS 16

// Workspace layout (floats):
//   sum_rgb : [0]       4096
//   sum_evt : [4096]    4096
//   MT      : [8192]    2*65536  MT[m][d*256+i] = sum_e Wq[e,i]Wk[e,d]
//   u       : [139264]  2*256
//   wv      : [139776]  2*256
//   s0      : [140288]  2
//   v       : [140292]  2*16*256
//   cc      : [148484]  2*16
#define WS_SUMR 0
#define WS_SUME 4096
#define WS_MT   8192
#define WS_U    139264
#define WS_WV   139776
#define WS_S0   140288
#define WS_V    140292
#define WS_C    148484

// ---- Phase 1: spatial column sums (blocks 0..4095; one (b,c) row of BOTH
//      arrays per block, 8 independent float4 loads per thread) + weight
//      precompute (blocks 4096..4607).
__global__ __launch_bounds__(256) void k_phase1(
    const float* __restrict__ rgb, const float* __restrict__ evt,
    const float* __restrict__ Wq_a, const float* __restrict__ bq_a,
    const float* __restrict__ Wk_a, const float* __restrict__ bk_a,
    const float* __restrict__ Wq_d, const float* __restrict__ bq_d,
    const float* __restrict__ Wk_d, const float* __restrict__ bk_d,
    float* __restrict__ ws) {
    int t = threadIdx.x;
    if (blockIdx.x < 4096) {
        int bc = blockIdx.x;
        const float4* r4 = (const float4*)(rgb + (size_t)bc * NPIX);
        const float4* e4 = (const float4*)(evt + (size_t)bc * NPIX);
        // 8 independent 16B loads, all in flight before any arithmetic
        float4 a0 = r4[t], a1 = r4[t + 256], a2 = r4[t + 512], a3 = r4[t + 768];
        float4 b0 = e4[t], b1 = e4[t + 256], b2 = e4[t + 512], b3 = e4[t + 768];
        float sr = ((a0.x + a0.y) + (a0.z + a0.w)) + ((a1.x + a1.y) + (a1.z + a1.w))
                 + ((a2.x + a2.y) + (a2.z + a2.w)) + ((a3.x + a3.y) + (a3.z + a3.w));
        float se = ((b0.x + b0.y) + (b0.z + b0.w)) + ((b1.x + b1.y) + (b1.z + b1.w))
                 + ((b2.x + b2.y) + (b2.z + b2.w)) + ((b3.x + b3.y) + (b3.z + b3.w));
        #pragma unroll
        for (int off = 32; off >= 1; off >>= 1) {
            sr += __shfl_down(sr, off, 64);
            se += __shfl_down(se, off, 64);
        }
        __shared__ float lr[4], le[4];
        int wid = t >> 6, lane = t & 63;
        if (lane == 0) { lr[wid] = sr; le[wid] = se; }
        __syncthreads();
        if (t == 0) {
            ws[WS_SUMR + bc] = (lr[0] + lr[1]) + (lr[2] + lr[3]);
            ws[WS_SUME + bc] = (le[0] + le[1]) + (le[2] + le[3]);
        }
    } else {
        int pid = blockIdx.x - 4096;
        int d = pid & 255, m = pid >> 8;
        const float* Wq = m ? Wq_d : Wq_a;
        const float* Wk = m ? Wk_d : Wk_a;
        const float* bq = m ? bq_d : bq_a;
        const float* bk = m ? bk_d : bk_a;
        int i = t;
        float acc = 0.f;
        #pragma unroll 8
        for (int e = 0; e < 256; ++e)
            acc += Wq[e * 256 + i] * Wk[e * 256 + d];
        ws[WS_MT + m * 65536 + d * 256 + i] = acc;
        float p = Wk[i * 256 + d] * bq[i];
        #pragma unroll
        for (int off = 32; off >= 1; off >>= 1) p += __shfl_down(p, off, 64);
        __shared__ float red[4];
        if ((t & 63) == 0) red[t >> 6] = p;
        __syncthreads();
        if (t == 0) ws[WS_WV + m * 256 + d] = (red[0] + red[1]) + (red[2] + red[3]);
        if (d == 0) {
            float ua = 0.f;
            #pragma unroll 8
            for (int e = 0; e < 256; ++e)
                ua += Wq[e * 256 + i] * bk[e];
            ws[WS_U + m * 256 + i] = 4096.0f * ua;
            float q = bq[i] * bk[i];
            #pragma unroll
            for (int off = 32; off >= 1; off >>= 1) q += __shfl_down(q, off, 64);
            __shared__ float red2[4];
            if ((t & 63) == 0) red2[t >> 6] = q;
            __syncthreads();
            if (t == 0) ws[WS_S0 + m] = 4096.0f * ((red2[0] + red2[1]) + (red2[2] + red2[3]));
        }
    }
}

// ---- Phase 2: per (b,branch) matvec over L2-hot MT: v = M S + u, c = w.S + s0
__global__ __launch_bounds__(256) void k_vvec2(float* __restrict__ ws) {
    int b = blockIdx.x, m = blockIdx.y;
    int i = threadIdx.x;
    const float* S = ws + (m ? WS_SUME : WS_SUMR) + b * 256;
    __shared__ float sS[256];
    sS[i] = S[i];
    __syncthreads();
    float acc = ws[WS_U + m * 256 + i];
    const float* Mp = ws + WS_MT + m * 65536;
    #pragma unroll 8
    for (int d = 0; d < 256; ++d)
        acc += Mp[d * 256 + i] * sS[d];
    ws[WS_V + (m * BS + b) * 256 + i] = acc;
    float p = ws[WS_WV + m * 256 + i] * sS[i];
    #pragma unroll
    for (int off = 32; off >= 1; off >>= 1) p += __shfl_down(p, off, 64);
    __shared__ float red[4];
    if ((i & 63) == 0) red[i >> 6] = p;
    __syncthreads();
    if (i == 0) ws[WS_C + m * BS + b] =
        (red[0] + red[1]) + (red[2] + red[3]) + ws[WS_S0 + m];
}

// ---- Phase 3: per-pixel dot / softmax / blend.
// Grid (64, 16): 64-pixel tiles, wave w owns channels [64w, 64w+64).
__global__ __launch_bounds__(256) void k_fuse(
    const float* __restrict__ rgb, const float* __restrict__ evt,
    const float* __restrict__ ws, float* __restrict__ out) {
    int b = blockIdx.y;
    int t = threadIdx.x;
    int wid = t >> 6, lane = t & 63;
    int n = blockIdx.x * 64 + lane;
    int c0 = wid * 64;
    __shared__ float s_va[DIM], s_vd[DIM];
    s_va[t] = ws[WS_V + b * 256 + t];
    s_vd[t] = ws[WS_V + (BS + b) * 256 + t];
    __syncthreads();
    const float* rb = rgb + (size_t)b * DIM * NPIX + n;
    const float* eb = evt + (size_t)b * DIM * NPIX + n;
    float acc_a = 0.f, acc_d = 0.f;
    #pragma unroll 16
    for (int c = 0; c < 64; ++c) {
        acc_a += rb[(size_t)(c0 + c) * NPIX] * s_va[c0 + c];
        acc_d += eb[(size_t)(c0 + c) * NPIX] * s_vd[c0 + c];
    }
    __shared__ float s_pa[4][64], s_pd[4][64];
    s_pa[wid][lane] = acc_a; s_pd[wid][lane] = acc_d;
    __syncthreads();
    float va = (s_pa[0][lane] + s_pa[1][lane] + s_pa[2][lane] + s_pa[3][lane]
                + ws[WS_C + b]) * 0.0625f;
    float vd = (s_pd[0][lane] + s_pd[1][lane] + s_pd[2][lane] + s_pd[3][lane]
                + ws[WS_C + BS + b]) * 0.0625f;
    float mm = fmaxf(va, vd);
    float ea = expf(va - mm), ed = expf(vd - mm);
    float inv = 1.0f / (ea + ed);
    float wa = ea * inv, wd = ed * inv;
    float* ob = out + (size_t)b * DIM * NPIX + n;
    #pragma unroll 16
    for (int c = 0; c < 64; ++c) {
        float x = rb[(size_t)(c0 + c) * NPIX];
        float y = eb[(size_t)(c0 + c) * NPIX];
        ob[(size_t)(c0 + c) * NPIX] = wa * x + wd * y;
    }
}

extern "C" void kernel_launch(void* const* d_in, const int* in_sizes, int n_in,
                              void* d_out, int out_size, void* d_ws, size_t ws_size,
                              hipStream_t stream) {
    const float* rgb  = (const float*)d_in[0];
    const float* evt  = (const float*)d_in[1];
    const float* Wq_a = (const float*)d_in[2];
    const float* bq_a = (const float*)d_in[3];
    const float* Wk_a = (const float*)d_in[4];
    const float* bk_a = (const float*)d_in[5];
    const float* Wq_d = (const float*)d_in[6];
    const float* bq_d = (const float*)d_in[7];
    const float* Wk_d = (const float*)d_in[8];
    const float* bk_d = (const float*)d_in[9];
    float* out = (float*)d_out;
    float* ws  = (float*)d_ws;

    k_phase1<<<4608, 256, 0, stream>>>(rgb, evt,
                                       Wq_a, bq_a, Wk_a, bk_a,
                                       Wq_d, bq_d, Wk_d, bk_d, ws);
    dim3 g2(BS, 2);
    k_vvec2<<<g2, 256, 0, stream>>>(ws);
    dim3 g3(NPIX / 64, BS);
    k_fuse<<<g3, 256, 0, stream>>>(rgb, evt, ws, out);
}

// Round 4
// 99.304 us; speedup vs baseline: 1.0623x; 1.0623x over previous
//
#include <hip/hip_runtime.h>

#define DIM 256
#define NPIX 4096
#define BS 16

// Workspace layout (floats):
//   sum_rgb : [0]      4096   (row index b*256+c)
//   sum_evt : [4096]   4096
//   v       : [8192]   2*16*256   v_{m,b}[i]
//   cc      : [16384]  2*16       c_{m,b}
#define WS_SUMR 0
#define WS_SUME 4096
#define WS_V    8192
#define WS_C    16384

// ---- Kernel 1: spatial row sums. 1024 blocks; block owns 8 consecutive rows
// of one array (rows 0..4095 = rgb, 512 blocks; 512..1023 -> evt).
// Wave w covers columns [w*1024, w*1024+1024); lane reads 4B, 256B/instr
// coalesced; 128 sustained loads per thread into 8 row accumulators.
__global__ __launch_bounds__(256) void k_colsum(const float* __restrict__ rgb,
                                                const float* __restrict__ evt,
                                                float* __restrict__ ws) {
    int j = blockIdx.x;
    int t = threadIdx.x, w = t >> 6, l = t & 63;
    const float* base;
    int row0, outbase;
    if (j < 512) { base = rgb; row0 = j * 8; outbase = WS_SUMR + row0; }
    else         { base = evt; row0 = (j - 512) * 8; outbase = WS_SUME + row0; }
    const float* p = base + (size_t)row0 * NPIX + w * 1024 + l;
    float acc[8];
    #pragma unroll
    for (int r = 0; r < 8; ++r) acc[r] = 0.f;
    #pragma unroll 4
    for (int k = 0; k < 16; ++k) {
        #pragma unroll
        for (int r = 0; r < 8; ++r)
            acc[r] += p[(size_t)r * NPIX + k * 64];
    }
    #pragma unroll
    for (int off = 32; off >= 1; off >>= 1) {
        #pragma unroll
        for (int r = 0; r < 8; ++r)
            acc[r] += __shfl_down(acc[r], off, 64);
    }
    __shared__ float sp[8][4];
    if (l == 0) {
        #pragma unroll
        for (int r = 0; r < 8; ++r) sp[r][w] = acc[r];
    }
    __syncthreads();
    if (t < 8)
        ws[outbase + t] = (sp[t][0] + sp[t][1]) + (sp[t][2] + sp[t][3]);
}

// ---- Kernel 2: per (b,branch): ksum = Wk.S + N*bk (wave-per-e, one float4
// per lane per e, fully coalesced), then v = Wq^T.ksum (thread-per-i, row
// broadcast), c = bq.ksum.
__global__ __launch_bounds__(256) void k_vvec(
    const float* __restrict__ Wq_a, const float* __restrict__ bq_a,
    const float* __restrict__ Wk_a, const float* __restrict__ bk_a,
    const float* __restrict__ Wq_d, const float* __restrict__ bq_d,
    const float* __restrict__ Wk_d, const float* __restrict__ bk_d,
    float* __restrict__ ws) {
    int b = blockIdx.x, m = blockIdx.y;
    const float* Wq = m ? Wq_d : Wq_a;
    const float* Wk = m ? Wk_d : Wk_a;
    const float* bq = m ? bq_d : bq_a;
    const float* bk = m ? bk_d : bk_a;
    int t = threadIdx.x, w = t >> 6, l = t & 63;
    __shared__ float sS[256], sK[256];
    sS[t] = ws[(m ? WS_SUME : WS_SUMR) + b * 256 + t];
    __syncthreads();
    float4 sv = ((const float4*)sS)[l];
    // wave w computes e in [w*64, w*64+64), 4 at a time (4 independent chains)
    for (int eo = 0; eo < 64; eo += 4) {
        int e = w * 64 + eo;
        float4 a0 = ((const float4*)(Wk + (size_t)(e + 0) * 256))[l];
        float4 a1 = ((const float4*)(Wk + (size_t)(e + 1) * 256))[l];
        float4 a2 = ((const float4*)(Wk + (size_t)(e + 2) * 256))[l];
        float4 a3 = ((const float4*)(Wk + (size_t)(e + 3) * 256))[l];
        float p0 = a0.x * sv.x + a0.y * sv.y + a0.z * sv.z + a0.w * sv.w;
        float p1 = a1.x * sv.x + a1.y * sv.y + a1.z * sv.z + a1.w * sv.w;
        float p2 = a2.x * sv.x + a2.y * sv.y + a2.z * sv.z + a2.w * sv.w;
        float p3 = a3.x * sv.x + a3.y * sv.y + a3.z * sv.z + a3.w * sv.w;
        #pragma unroll
        for (int off = 32; off >= 1; off >>= 1) {
            p0 += __shfl_down(p0, off, 64);
            p1 += __shfl_down(p1, off, 64);
            p2 += __shfl_down(p2, off, 64);
            p3 += __shfl_down(p3, off, 64);
        }
        if (l == 0) {
            sK[e + 0] = p0 + 4096.0f * bk[e + 0];
            sK[e + 1] = p1 + 4096.0f * bk[e + 1];
            sK[e + 2] = p2 + 4096.0f * bk[e + 2];
            sK[e + 3] = p3 + 4096.0f * bk[e + 3];
        }
    }
    __syncthreads();
    // v[i] = sum_e Wq[e,i] * ksum[e]   (coalesced column access)
    float acc = 0.f;
    #pragma unroll 8
    for (int e = 0; e < 256; ++e)
        acc += Wq[(size_t)e * 256 + t] * sK[e];
    ws[WS_V + (m * BS + b) * 256 + t] = acc;
    // c = bq . ksum
    float pc = bq[t] * sK[t];
    #pragma unroll
    for (int off = 32; off >= 1; off >>= 1) pc += __shfl_down(pc, off, 64);
    __shared__ float red[4];
    if (l == 0) red[w] = pc;
    __syncthreads();
    if (t == 0)
        ws[WS_C + m * BS + b] = (red[0] + red[1]) + (red[2] + red[3]);
}

// ---- Kernel 3: per-pixel dot / softmax / blend (unchanged structure).
__global__ __launch_bounds__(256) void k_fuse(
    const float* __restrict__ rgb, const float* __restrict__ evt,
    const float* __restrict__ ws, float* __restrict__ out) {
    int b = blockIdx.y;
    int t = threadIdx.x;
    int wid = t >> 6, lane = t & 63;
    int n = blockIdx.x * 64 + lane;
    int c0 = wid * 64;
    __shared__ float s_va[DIM], s_vd[DIM];
    s_va[t] = ws[WS_V + b * 256 + t];
    s_vd[t] = ws[WS_V + (BS + b) * 256 + t];
    __syncthreads();
    const float* rb = rgb + (size_t)b * DIM * NPIX + n;
    const float* eb = evt + (size_t)b * DIM * NPIX + n;
    float acc_a = 0.f, acc_d = 0.f;
    #pragma unroll 16
    for (int c = 0; c < 64; ++c) {
        acc_a += rb[(size_t)(c0 + c) * NPIX] * s_va[c0 + c];
        acc_d += eb[(size_t)(c0 + c) * NPIX] * s_vd[c0 + c];
    }
    __shared__ float s_pa[4][64], s_pd[4][64];
    s_pa[wid][lane] = acc_a; s_pd[wid][lane] = acc_d;
    __syncthreads();
    float va = (s_pa[0][lane] + s_pa[1][lane] + s_pa[2][lane] + s_pa[3][lane]
                + ws[WS_C + b]) * 0.0625f;
    float vd = (s_pd[0][lane] + s_pd[1][lane] + s_pd[2][lane] + s_pd[3][lane]
                + ws[WS_C + BS + b]) * 0.0625f;
    float mm = fmaxf(va, vd);
    float ea = expf(va - mm), ed = expf(vd - mm);
    float inv = 1.0f / (ea + ed);
    float wa = ea * inv, wd = ed * inv;
    float* ob = out + (size_t)b * DIM * NPIX + n;
    #pragma unroll 16
    for (int c = 0; c < 64; ++c) {
        float x = rb[(size_t)(c0 + c) * NPIX];
        float y = eb[(size_t)(c0 + c) * NPIX];
        ob[(size_t)(c0 + c) * NPIX] = wa * x + wd * y;
    }
}

extern "C" void kernel_launch(void* const* d_in, const int* in_sizes, int n_in,
                              void* d_out, int out_size, void* d_ws, size_t ws_size,
                              hipStream_t stream) {
    const float* rgb  = (const float*)d_in[0];
    const float* evt  = (const float*)d_in[1];
    const float* Wq_a = (const float*)d_in[2];
    const float* bq_a = (const float*)d_in[3];
    const float* Wk_a = (const float*)d_in[4];
    const float* bk_a = (const float*)d_in[5];
    const float* Wq_d = (const float*)d_in[6];
    const float* bq_d = (const float*)d_in[7];
    const float* Wk_d = (const float*)d_in[8];
    const float* bk_d = (const float*)d_in[9];
    float* out = (float*)d_out;
    float* ws  = (float*)d_ws;

    k_colsum<<<1024, 256, 0, stream>>>(rgb, evt, ws);
    dim3 g2(BS, 2);
    k_vvec<<<g2, 256, 0, stream>>>(Wq_a, bq_a, Wk_a, bk_a,
                                   Wq_d, bq_d, Wk_d, bk_d, ws);
    dim3 g3(NPIX / 64, BS);
    k_fuse<<<g3, 256, 0, stream>>>(rgb, evt, ws, out);
}

// Round 5
// 97.182 us; speedup vs baseline: 1.0855x; 1.0218x over previous
//
#include <hip/hip_runtime.h>

#define DIM 256
#define NPIX 4096
#define BS 16

#define WS_SUMR 0
#define WS_SUME 4096
#define WS_V    8192
#define WS_C    16384

// ---- Kernel 1: spatial row sums. 2048 blocks; block owns 4 rows (16 KB each)
// of one array. Each thread: 16 independent float4 loads (4 per row), all in
// flight before any arithmetic. Per-wave in-flight = 16 KB.
__global__ __launch_bounds__(256) void k_colsum(const float* __restrict__ rgb,
                                                const float* __restrict__ evt,
                                                float* __restrict__ ws) {
    int j = blockIdx.x;
    int t = threadIdx.x, w = t >> 6, l = t & 63;
    const float* base;
    int row0, outbase;
    if (j < 1024) { base = rgb; row0 = j * 4; outbase = WS_SUMR + row0; }
    else          { base = evt; row0 = (j - 1024) * 4; outbase = WS_SUME + row0; }
    const float4* p = (const float4*)(base + (size_t)row0 * NPIX);
    // row r occupies float4 indices [r*1024, r*1024+1024); thread covers
    // k*256+t for k=0..3 in each row. 16 independent loads.
    float4 v0  = p[0 * 1024 + 0 * 256 + t];
    float4 v1  = p[0 * 1024 + 1 * 256 + t];
    float4 v2  = p[0 * 1024 + 2 * 256 + t];
    float4 v3  = p[0 * 1024 + 3 * 256 + t];
    float4 v4  = p[1 * 1024 + 0 * 256 + t];
    float4 v5  = p[1 * 1024 + 1 * 256 + t];
    float4 v6  = p[1 * 1024 + 2 * 256 + t];
    float4 v7  = p[1 * 1024 + 3 * 256 + t];
    float4 v8  = p[2 * 1024 + 0 * 256 + t];
    float4 v9  = p[2 * 1024 + 1 * 256 + t];
    float4 v10 = p[2 * 1024 + 2 * 256 + t];
    float4 v11 = p[2 * 1024 + 3 * 256 + t];
    float4 v12 = p[3 * 1024 + 0 * 256 + t];
    float4 v13 = p[3 * 1024 + 1 * 256 + t];
    float4 v14 = p[3 * 1024 + 2 * 256 + t];
    float4 v15 = p[3 * 1024 + 3 * 256 + t];
    float s0 = ((v0.x + v0.y) + (v0.z + v0.w)) + ((v1.x + v1.y) + (v1.z + v1.w))
             + ((v2.x + v2.y) + (v2.z + v2.w)) + ((v3.x + v3.y) + (v3.z + v3.w));
    float s1 = ((v4.x + v4.y) + (v4.z + v4.w)) + ((v5.x + v5.y) + (v5.z + v5.w))
             + ((v6.x + v6.y) + (v6.z + v6.w)) + ((v7.x + v7.y) + (v7.z + v7.w));
    float s2 = ((v8.x + v8.y) + (v8.z + v8.w)) + ((v9.x + v9.y) + (v9.z + v9.w))
             + ((v10.x + v10.y) + (v10.z + v10.w)) + ((v11.x + v11.y) + (v11.z + v11.w));
    float s3 = ((v12.x + v12.y) + (v12.z + v12.w)) + ((v13.x + v13.y) + (v13.z + v13.w))
             + ((v14.x + v14.y) + (v14.z + v14.w)) + ((v15.x + v15.y) + (v15.z + v15.w));
    #pragma unroll
    for (int off = 32; off >= 1; off >>= 1) {
        s0 += __shfl_down(s0, off, 64);
        s1 += __shfl_down(s1, off, 64);
        s2 += __shfl_down(s2, off, 64);
        s3 += __shfl_down(s3, off, 64);
    }
    __shared__ float sp[4][4];
    if (l == 0) { sp[0][w] = s0; sp[1][w] = s1; sp[2][w] = s2; sp[3][w] = s3; }
    __syncthreads();
    if (t < 4)
        ws[outbase + t] = (sp[t][0] + sp[t][1]) + (sp[t][2] + sp[t][3]);
}

// ---- Kernel 2: per (b,branch): ksum = Wk.S + N*bk, v = Wq^T.ksum, c = bq.ksum
__global__ __launch_bounds__(256) void k_vvec(
    const float* __restrict__ Wq_a, const float* __restrict__ bq_a,
    const float* __restrict__ Wk_a, const float* __restrict__ bk_a,
    const float* __restrict__ Wq_d, const float* __restrict__ bq_d,
    const float* __restrict__ Wk_d, const float* __restrict__ bk_d,
    float* __restrict__ ws) {
    int b = blockIdx.x, m = blockIdx.y;
    const float* Wq = m ? Wq_d : Wq_a;
    const float* Wk = m ? Wk_d : Wk_a;
    const float* bq = m ? bq_d : bq_a;
    const float* bk = m ? bk_d : bk_a;
    int t = threadIdx.x, w = t >> 6, l = t & 63;
    __shared__ float sS[256], sK[256];
    sS[t] = ws[(m ? WS_SUME : WS_SUMR) + b * 256 + t];
    __syncthreads();
    float4 sv = ((const float4*)sS)[l];
    for (int eo = 0; eo < 64; eo += 4) {
        int e = w * 64 + eo;
        float4 a0 = ((const float4*)(Wk + (size_t)(e + 0) * 256))[l];
        float4 a1 = ((const float4*)(Wk + (size_t)(e + 1) * 256))[l];
        float4 a2 = ((const float4*)(Wk + (size_t)(e + 2) * 256))[l];
        float4 a3 = ((const float4*)(Wk + (size_t)(e + 3) * 256))[l];
        float p0 = a0.x * sv.x + a0.y * sv.y + a0.z * sv.z + a0.w * sv.w;
        float p1 = a1.x * sv.x + a1.y * sv.y + a1.z * sv.z + a1.w * sv.w;
        float p2 = a2.x * sv.x + a2.y * sv.y + a2.z * sv.z + a2.w * sv.w;
        float p3 = a3.x * sv.x + a3.y * sv.y + a3.z * sv.z + a3.w * sv.w;
        #pragma unroll
        for (int off = 32; off >= 1; off >>= 1) {
            p0 += __shfl_down(p0, off, 64);
            p1 += __shfl_down(p1, off, 64);
            p2 += __shfl_down(p2, off, 64);
            p3 += __shfl_down(p3, off, 64);
        }
        if (l == 0) {
            sK[e + 0] = p0 + 4096.0f * bk[e + 0];
            sK[e + 1] = p1 + 4096.0f * bk[e + 1];
            sK[e + 2] = p2 + 4096.0f * bk[e + 2];
            sK[e + 3] = p3 + 4096.0f * bk[e + 3];
        }
    }
    __syncthreads();
    float acc = 0.f;
    #pragma unroll 8
    for (int e = 0; e < 256; ++e)
        acc += Wq[(size_t)e * 256 + t] * sK[e];
    ws[WS_V + (m * BS + b) * 256 + t] = acc;
    float pc = bq[t] * sK[t];
    #pragma unroll
    for (int off = 32; off >= 1; off >>= 1) pc += __shfl_down(pc, off, 64);
    __shared__ float red[4];
    if (l == 0) red[w] = pc;
    __syncthreads();
    if (t == 0)
        ws[WS_C + m * BS + b] = (red[0] + red[1]) + (red[2] + red[3]);
}

// ---- Kernel 3: per-pixel dot / softmax / blend (unchanged).
__global__ __launch_bounds__(256) void k_fuse(
    const float* __restrict__ rgb, const float* __restrict__ evt,
    const float* __restrict__ ws, float* __restrict__ out) {
    int b = blockIdx.y;
    int t = threadIdx.x;
    int wid = t >> 6, lane = t & 63;
    int n = blockIdx.x * 64 + lane;
    int c0 = wid * 64;
    __shared__ float s_va[DIM], s_vd[DIM];
    s_va[t] = ws[WS_V + b * 256 + t];
    s_vd[t] = ws[WS_V + (BS + b) * 256 + t];
    __syncthreads();
    const float* rb = rgb + (size_t)b * DIM * NPIX + n;
    const float* eb = evt + (size_t)b * DIM * NPIX + n;
    float acc_a = 0.f, acc_d = 0.f;
    #pragma unroll 16
    for (int c = 0; c < 64; ++c) {
        acc_a += rb[(size_t)(c0 + c) * NPIX] * s_va[c0 + c];
        acc_d += eb[(size_t)(c0 + c) * NPIX] * s_vd[c0 + c];
    }
    __shared__ float s_pa[4][64], s_pd[4][64];
    s_pa[wid][lane] = acc_a; s_pd[wid][lane] = acc_d;
    __syncthreads();
    float va = (s_pa[0][lane] + s_pa[1][lane] + s_pa[2][lane] + s_pa[3][lane]
                + ws[WS_C + b]) * 0.0625f;
    float vd = (s_pd[0][lane] + s_pd[1][lane] + s_pd[2][lane] + s_pd[3][lane]
                + ws[WS_C + BS + b]) * 0.0625f;
    float mm = fmaxf(va, vd);
    float ea = expf(va - mm), ed = expf(vd - mm);
    float inv = 1.0f / (ea + ed);
    float wa = ea * inv, wd = ed * inv;
    float* ob = out + (size_t)b * DIM * NPIX + n;
    #pragma unroll 16
    for (int c = 0; c < 64; ++c) {
        float x = rb[(size_t)(c0 + c) * NPIX];
        float y = eb[(size_t)(c0 + c) * NPIX];
        ob[(size_t)(c0 + c) * NPIX] = wa * x + wd * y;
    }
}

extern "C" void kernel_launch(void* const* d_in, const int* in_sizes, int n_in,
                              void* d_out, int out_size, void* d_ws, size_t ws_size,
                              hipStream_t stream) {
    const float* rgb  = (const float*)d_in[0];
    const float* evt  = (const float*)d_in[1];
    const float* Wq_a = (const float*)d_in[2];
    const float* bq_a = (const float*)d_in[3];
    const float* Wk_a = (const float*)d_in[4];
    const float* bk_a = (const float*)d_in[5];
    const float* Wq_d = (const float*)d_in[6];
    const float* bq_d = (const float*)d_in[7];
    const float* Wk_d = (const float*)d_in[8];
    const float* bk_d = (const float*)d_in[9];
    float* out = (float*)d_out;
    float* ws  = (float*)d_ws;

    k_colsum<<<2048, 256, 0, stream>>>(rgb, evt, ws);
    dim3 g2(BS, 2);
    k_vvec<<<g2, 256, 0, stream>>>(Wq_a, bq_a, Wk_a, bk_a,
                                   Wq_d, bq_d, Wk_d, bk_d, ws);
    dim3 g3(NPIX / 64, BS);
    k_fuse<<<g3, 256, 0, stream>>>(rgb, evt, ws, out);
}

// Round 6
// 92.186 us; speedup vs baseline: 1.1443x; 1.0542x over previous
//
#include <hip/hip_runtime.h>

#define DIM 256
#define NPIX 4096
#define BS 16

#define WS_SUMR 0
#define WS_SUME 4096
#define WS_V    8192
#define WS_C    16384

// ---- Kernel 1: spatial row sums. 2048 blocks; block owns 4 rows of one
// array. 16 independent float4 loads pinned in flight by a compiler barrier.
__global__ __launch_bounds__(256) void k_colsum(const float* __restrict__ rgb,
                                                const float* __restrict__ evt,
                                                float* __restrict__ ws) {
    int j = blockIdx.x;
    int t = threadIdx.x, w = t >> 6, l = t & 63;
    const float* base;
    int row0, outbase;
    if (j < 1024) { base = rgb; row0 = j * 4; outbase = WS_SUMR + row0; }
    else          { base = evt; row0 = (j - 1024) * 4; outbase = WS_SUME + row0; }
    const float4* p = (const float4*)(base + (size_t)row0 * NPIX);
    float4 v0  = p[0 * 1024 + 0 * 256 + t];
    float4 v1  = p[0 * 1024 + 1 * 256 + t];
    float4 v2  = p[0 * 1024 + 2 * 256 + t];
    float4 v3  = p[0 * 1024 + 3 * 256 + t];
    float4 v4  = p[1 * 1024 + 0 * 256 + t];
    float4 v5  = p[1 * 1024 + 1 * 256 + t];
    float4 v6  = p[1 * 1024 + 2 * 256 + t];
    float4 v7  = p[1 * 1024 + 3 * 256 + t];
    float4 v8  = p[2 * 1024 + 0 * 256 + t];
    float4 v9  = p[2 * 1024 + 1 * 256 + t];
    float4 v10 = p[2 * 1024 + 2 * 256 + t];
    float4 v11 = p[2 * 1024 + 3 * 256 + t];
    float4 v12 = p[3 * 1024 + 0 * 256 + t];
    float4 v13 = p[3 * 1024 + 1 * 256 + t];
    float4 v14 = p[3 * 1024 + 2 * 256 + t];
    float4 v15 = p[3 * 1024 + 3 * 256 + t];
    asm volatile("" ::: "memory");   // pin all 16 loads before any consumption
    float s0 = ((v0.x + v0.y) + (v0.z + v0.w)) + ((v1.x + v1.y) + (v1.z + v1.w))
             + ((v2.x + v2.y) + (v2.z + v2.w)) + ((v3.x + v3.y) + (v3.z + v3.w));
    float s1 = ((v4.x + v4.y) + (v4.z + v4.w)) + ((v5.x + v5.y) + (v5.z + v5.w))
             + ((v6.x + v6.y) + (v6.z + v6.w)) + ((v7.x + v7.y) + (v7.z + v7.w));
    float s2 = ((v8.x + v8.y) + (v8.z + v8.w)) + ((v9.x + v9.y) + (v9.z + v9.w))
             + ((v10.x + v10.y) + (v10.z + v10.w)) + ((v11.x + v11.y) + (v11.z + v11.w));
    float s3 = ((v12.x + v12.y) + (v12.z + v12.w)) + ((v13.x + v13.y) + (v13.z + v13.w))
             + ((v14.x + v14.y) + (v14.z + v14.w)) + ((v15.x + v15.y) + (v15.z + v15.w));
    #pragma unroll
    for (int off = 32; off >= 1; off >>= 1) {
        s0 += __shfl_down(s0, off, 64);
        s1 += __shfl_down(s1, off, 64);
        s2 += __shfl_down(s2, off, 64);
        s3 += __shfl_down(s3, off, 64);
    }
    __shared__ float sp[4][4];
    if (l == 0) { sp[0][w] = s0; sp[1][w] = s1; sp[2][w] = s2; sp[3][w] = s3; }
    __syncthreads();
    if (t < 4)
        ws[outbase + t] = (sp[t][0] + sp[t][1]) + (sp[t][2] + sp[t][3]);
}

// ---- Kernel 2: per (b,branch): ksum = Wk.S + N*bk, v = Wq^T.ksum, c = bq.ksum
__global__ __launch_bounds__(256) void k_vvec(
    const float* __restrict__ Wq_a, const float* __restrict__ bq_a,
    const float* __restrict__ Wk_a, const float* __restrict__ bk_a,
    const float* __restrict__ Wq_d, const float* __restrict__ bq_d,
    const float* __restrict__ Wk_d, const float* __restrict__ bk_d,
    float* __restrict__ ws) {
    int b = blockIdx.x, m = blockIdx.y;
    const float* Wq = m ? Wq_d : Wq_a;
    const float* Wk = m ? Wk_d : Wk_a;
    const float* bq = m ? bq_d : bq_a;
    const float* bk = m ? bk_d : bk_a;
    int t = threadIdx.x, w = t >> 6, l = t & 63;
    __shared__ float sS[256], sK[256];
    sS[t] = ws[(m ? WS_SUME : WS_SUMR) + b * 256 + t];
    __syncthreads();
    float4 sv = ((const float4*)sS)[l];
    for (int eo = 0; eo < 64; eo += 4) {
        int e = w * 64 + eo;
        float4 a0 = ((const float4*)(Wk + (size_t)(e + 0) * 256))[l];
        float4 a1 = ((const float4*)(Wk + (size_t)(e + 1) * 256))[l];
        float4 a2 = ((const float4*)(Wk + (size_t)(e + 2) * 256))[l];
        float4 a3 = ((const float4*)(Wk + (size_t)(e + 3) * 256))[l];
        float p0 = a0.x * sv.x + a0.y * sv.y + a0.z * sv.z + a0.w * sv.w;
        float p1 = a1.x * sv.x + a1.y * sv.y + a1.z * sv.z + a1.w * sv.w;
        float p2 = a2.x * sv.x + a2.y * sv.y + a2.z * sv.z + a2.w * sv.w;
        float p3 = a3.x * sv.x + a3.y * sv.y + a3.z * sv.z + a3.w * sv.w;
        #pragma unroll
        for (int off = 32; off >= 1; off >>= 1) {
            p0 += __shfl_down(p0, off, 64);
            p1 += __shfl_down(p1, off, 64);
            p2 += __shfl_down(p2, off, 64);
            p3 += __shfl_down(p3, off, 64);
        }
        if (l == 0) {
            sK[e + 0] = p0 + 4096.0f * bk[e + 0];
            sK[e + 1] = p1 + 4096.0f * bk[e + 1];
            sK[e + 2] = p2 + 4096.0f * bk[e + 2];
            sK[e + 3] = p3 + 4096.0f * bk[e + 3];
        }
    }
    __syncthreads();
    float acc = 0.f;
    #pragma unroll 8
    for (int e = 0; e < 256; ++e)
        acc += Wq[(size_t)e * 256 + t] * sK[e];
    ws[WS_V + (m * BS + b) * 256 + t] = acc;
    float pc = bq[t] * sK[t];
    #pragma unroll
    for (int off = 32; off >= 1; off >>= 1) pc += __shfl_down(pc, off, 64);
    __shared__ float red[4];
    if (l == 0) red[w] = pc;
    __syncthreads();
    if (t == 0)
        ws[WS_C + m * BS + b] = (red[0] + red[1]) + (red[2] + red[3]);
}

// ---- Kernel 3: per-pixel dot / softmax / blend. Batched loads (8 per array)
// with compiler barriers; 2 accumulators per array for ILP.
__global__ __launch_bounds__(256) void k_fuse(
    const float* __restrict__ rgb, const float* __restrict__ evt,
    const float* __restrict__ ws, float* __restrict__ out) {
    int b = blockIdx.y;
    int t = threadIdx.x;
    int wid = t >> 6, lane = t & 63;
    int n = blockIdx.x * 64 + lane;
    int c0 = wid * 64;
    __shared__ float s_va[DIM], s_vd[DIM];
    s_va[t] = ws[WS_V + b * 256 + t];
    s_vd[t] = ws[WS_V + (BS + b) * 256 + t];
    __syncthreads();
    const float* rb = rgb + (size_t)b * DIM * NPIX + n;
    const float* eb = evt + (size_t)b * DIM * NPIX + n;
    float a0 = 0.f, a1 = 0.f, d0 = 0.f, d1 = 0.f;
    #pragma unroll
    for (int cb = 0; cb < 64; cb += 8) {
        float xa[8], xd[8];
        #pragma unroll
        for (int u = 0; u < 8; ++u) xa[u] = rb[(size_t)(c0 + cb + u) * NPIX];
        #pragma unroll
        for (int u = 0; u < 8; ++u) xd[u] = eb[(size_t)(c0 + cb + u) * NPIX];
        asm volatile("" ::: "memory");
        #pragma unroll
        for (int u = 0; u < 8; u += 2) {
            a0 += xa[u]     * s_va[c0 + cb + u];
            a1 += xa[u + 1] * s_va[c0 + cb + u + 1];
            d0 += xd[u]     * s_vd[c0 + cb + u];
            d1 += xd[u + 1] * s_vd[c0 + cb + u + 1];
        }
    }
    float acc_a = a0 + a1, acc_d = d0 + d1;
    __shared__ float s_pa[4][64], s_pd[4][64];
    s_pa[wid][lane] = acc_a; s_pd[wid][lane] = acc_d;
    __syncthreads();
    float va = (s_pa[0][lane] + s_pa[1][lane] + s_pa[2][lane] + s_pa[3][lane]
                + ws[WS_C + b]) * 0.0625f;
    float vd = (s_pd[0][lane] + s_pd[1][lane] + s_pd[2][lane] + s_pd[3][lane]
                + ws[WS_C + BS + b]) * 0.0625f;
    float mm = fmaxf(va, vd);
    float ea = expf(va - mm), ed = expf(vd - mm);
    float inv = 1.0f / (ea + ed);
    float wa = ea * inv, wd = ed * inv;
    float* ob = out + (size_t)b * DIM * NPIX + n;
    #pragma unroll
    for (int cb = 0; cb < 64; cb += 8) {
        float xa[8], xd[8];
        #pragma unroll
        for (int u = 0; u < 8; ++u) xa[u] = rb[(size_t)(c0 + cb + u) * NPIX];
        #pragma unroll
        for (int u = 0; u < 8; ++u) xd[u] = eb[(size_t)(c0 + cb + u) * NPIX];
        asm volatile("" ::: "memory");
        #pragma unroll
        for (int u = 0; u < 8; ++u)
            ob[(size_t)(c0 + cb + u) * NPIX] = wa * xa[u] + wd * xd[u];
    }
}

extern "C" void kernel_launch(void* const* d_in, const int* in_sizes, int n_in,
                              void* d_out, int out_size, void* d_ws, size_t ws_size,
                              hipStream_t stream) {
    const float* rgb  = (const float*)d_in[0];
    const float* evt  = (const float*)d_in[1];
    const float* Wq_a = (const float*)d_in[2];
    const float* bq_a = (const float*)d_in[3];
    const float* Wk_a = (const float*)d_in[4];
    const float* bk_a = (const float*)d_in[5];
    const float* Wq_d = (const float*)d_in[6];
    const float* bq_d = (const float*)d_in[7];
    const float* Wk_d = (const float*)d_in[8];
    const float* bk_d = (const float*)d_in[9];
    float* out = (float*)d_out;
    float* ws  = (float*)d_ws;

    k_colsum<<<2048, 256, 0, stream>>>(rgb, evt, ws);
    dim3 g2(BS, 2);
    k_vvec<<<g2, 256, 0, stream>>>(Wq_a, bq_a, Wk_a, bk_a,
                                   Wq_d, bq_d, Wk_d, bk_d, ws);
    dim3 g3(NPIX / 64, BS);
    k_fuse<<<g3, 256, 0, stream>>>(rgb, evt, ws, out);
}